// Round 1
// 778.854 us; speedup vs baseline: 1.1878x; 1.1878x over previous
//
#include <hip/hip_runtime.h>
#include <hip/hip_bf16.h>
#include <math.h>

// Problem constants
#define BN   16
#define NCH  64      // CIN == COUT == 64
#define HH   256
#define WW   256
#define M0_  20
#define M1_  20

// Workspace layout (in floats)
#define TWA_OFF 0
#define TWA_SZ  (256*40)            // [w][l] (cos, -sin) pairs
#define TWB_OFF (TWA_OFF + TWA_SZ)
#define TWB_SZ  (20*256*2)          // [k][h] (cos, -sin)/256 pairs
#define YW_OFF  (TWB_OFF + TWB_SZ)
#define YW_SZ   (1024*256*40)       // [b*64+i][h][l] complex interleaved
#define X_OFF   (YW_OFF + YW_SZ)
#define X_SZ    (1024*800)          // [b*64+i][k*20+l] complex
#define OF_OFF  (X_OFF + X_SZ)
#define OF_SZ   (1024*800)          // [b*64+o][k*20+l] complex (scaled)
#define Z_OFF   (OF_OFF + OF_SZ)
#define Z_SZ    (1024*256*40)       // [b*64+o][h][l] complex interleaved

// ---------------- twiddle tables ----------------
__global__ __launch_bounds__(256) void k_init(float* __restrict__ twA, float* __restrict__ twB){
  int t = blockIdx.x*256 + threadIdx.x;
  if (t >= 5120) return;
  const float step = 6.28318530717958647692f / 256.0f;
  {
    int w = t / 20, l = t % 20;
    int m = (w*l) & 255;
    float a = step * (float)m;
    twA[2*t]   =  cosf(a);
    twA[2*t+1] = -sinf(a);
  }
  {
    int k = t >> 8, h = t & 255;
    int m = (k*h) & 255;
    float a = step * (float)m;
    twB[2*t]   =  cosf(a) * (1.0f/256.0f);
    twB[2*t+1] = -sinf(a) * (1.0f/256.0f);
  }
}

// ---------------- stage A: DFT along w (20 modes) ----------------
__global__ __launch_bounds__(256) void k_dftw(const float* __restrict__ x,
                                              const float* __restrict__ twA,
                                              float* __restrict__ Yw){
  __shared__ float4 tws[2560];   // 40KB
  for (int r = threadIdx.x; r < 2560; r += 256) tws[r] = ((const float4*)twA)[r];
  __syncthreads();
  int bi = blockIdx.x;           // b*64+i
  int h  = threadIdx.x;
  const float4* row4 = (const float4*)(x + (((size_t)bi*256 + h) * 256));
  float acc[40];
#pragma unroll
  for (int j=0;j<40;j++) acc[j] = 0.f;
  for (int w4 = 0; w4 < 64; ++w4){
    float4 xv = row4[w4];
#pragma unroll
    for (int s=0;s<4;s++){
      float xvs = (s==0)?xv.x:((s==1)?xv.y:((s==2)?xv.z:xv.w));
      const float4* tp = &tws[(w4*4+s)*10];
#pragma unroll
      for (int p=0;p<10;p++){
        float4 tv = tp[p];
        acc[4*p+0] += xvs*tv.x;
        acc[4*p+1] += xvs*tv.y;
        acc[4*p+2] += xvs*tv.z;
        acc[4*p+3] += xvs*tv.w;
      }
    }
  }
  float4* dst = (float4*)(Yw + (((size_t)bi*256 + h) * 40));
#pragma unroll
  for (int p=0;p<10;p++) dst[p] = make_float4(acc[4*p],acc[4*p+1],acc[4*p+2],acc[4*p+3]);
}

// ---------------- stage B: DFT along h (20 modes) ----------------
__global__ __launch_bounds__(512) void k_dfth(const float* __restrict__ Yw,
                                              const float* __restrict__ twB,
                                              float* __restrict__ X){
  __shared__ float4 yws4[2560];  // 40KB
  int bi = blockIdx.x;
  const float4* src = (const float4*)(Yw + (size_t)bi*10240);
  for (int r = threadIdx.x; r < 2560; r += 512) yws4[r] = src[r];
  __syncthreads();
  int t = threadIdx.x;
  if (t < 400){
    int k = t / 20, l = t % 20;
    const float2* yw2 = (const float2*)yws4;
    const float2* tb  = ((const float2*)twB) + k*256;
    float are = 0.f, aim = 0.f;
    for (int h=0; h<256; ++h){
      float2 tv = tb[h];
      float2 yv = yw2[h*20 + l];
      are += yv.x*tv.x - yv.y*tv.y;
      aim += yv.x*tv.y + yv.y*tv.x;
    }
    ((float2*)X)[(size_t)bi*400 + t] = make_float2(are, aim);
  }
}

// ---------------- stage C: per-mode channel mix ----------------
__global__ __launch_bounds__(256) void k_mix(const float* __restrict__ X,
                                             const float* __restrict__ wre,
                                             const float* __restrict__ wim,
                                             float* __restrict__ OF){
  __shared__ float2 Xs[1024];
  int bk = blockIdx.x;
  int kl = (bk & 7)*50 + (bk >> 3);
  const float2* X2 = (const float2*)X;
  for (int r = threadIdx.x; r < 1024; r += 256) Xs[r] = X2[(size_t)r*400 + kl];
  __syncthreads();
  int o = threadIdx.x & 63, bg = threadIdx.x >> 6;
  float ar[4] = {0,0,0,0}, ai[4] = {0,0,0,0};
  for (int i=0;i<64;++i){
    size_t widx = (size_t)(i*64 + o)*400 + kl;
    float wr = wre[widx], wi = wim[widx];
#pragma unroll
    for (int j=0;j<4;j++){
      float2 xv = Xs[(bg*4+j)*64 + i];
      ar[j] += xv.x*wr - xv.y*wi;
      ai[j] += xv.x*wi + xv.y*wr;
    }
  }
  int l = kl % 20;
  float scale = (l==0 ? 1.0f : 2.0f) * (1.0f/256.0f);
  float2* OF2 = (float2*)OF;
#pragma unroll
  for (int j=0;j<4;j++){
    OF2[(size_t)((bg*4+j)*64 + o)*400 + kl] = make_float2(ar[j]*scale, ai[j]*scale);
  }
}

// ---------------- stage D: zero-padded inverse DFT along h ----------------
__global__ __launch_bounds__(256) void k_idfth(const float* __restrict__ OF,
                                               float* __restrict__ Z){
  __shared__ float2 fs[400];
  int bo = blockIdx.x;
  const float2* src = ((const float2*)OF) + (size_t)bo*400;
  for (int r = threadIdx.x; r < 400; r += 256) fs[r] = src[r];
  __syncthreads();
  int h = threadIdx.x;
  float s1, c1;
  sincosf((float)h * 0.02454369260617025967f, &s1, &c1);
  float zr[20], zi[20];
#pragma unroll
  for (int l=0;l<20;l++){ zr[l]=0.f; zi[l]=0.f; }
  float tr = 1.f, ti = 0.f;
  for (int k=0;k<20;++k){
#pragma unroll
    for (int l=0;l<20;l++){
      float2 f = fs[k*20+l];
      zr[l] += f.x*tr - f.y*ti;
      zi[l] += f.x*ti + f.y*tr;
    }
    float nt = tr*c1 - ti*s1;
    ti = tr*s1 + ti*c1;
    tr = nt;
  }
  float4* dst = (float4*)(Z + (((size_t)bo*256 + h)*40));
#pragma unroll
  for (int p=0;p<10;p++) dst[p] = make_float4(zr[2*p], zi[2*p], zr[2*p+1], zi[2*p+1]);
}

// ---------------- stage E (MFMA): conv(hi+lo) + spectral irfft-w + GELU ----------------
// Per block (b,h):  D[o,w] = sum_k A[o,k]*B[k,w] + cb[o],  K = 192
//   A kt0,1 : bf16-hi of cw[o][i]          B: x_bf16[i][w]
//   A kt2,3 : bf16-lo of cw[o][i]          B: x_bf16[i][w]  (same LDS rows)
//   A kt4,5 : (zr,zi) pairs from Z         B: (cos_l, -sin_l)[w] pairs
// LDS B as packed bf16 k-pairs: dword (k2,w) at xp[k2*256 + ((w + 4*k2)&255)]
//   rows 0..31 = x pairs (i=2k2, 2k2+1); rows 32..51 = trig pairs l=k2-32.

typedef __attribute__((ext_vector_type(8))) short short8;
typedef __attribute__((ext_vector_type(4))) float f32x4;
union FI4 { int4 i; short8 s; };

__device__ __forceinline__ unsigned short bfh(float f){
  union { float f; unsigned u; } v; v.f = f;
  unsigned r = v.u + 0x7FFFu + ((v.u >> 16) & 1u);   // RNE to bf16
  return (unsigned short)(r >> 16);
}
__device__ __forceinline__ float bf2f(unsigned short s){
  union { unsigned u; float f; } v; v.u = ((unsigned)s) << 16;
  return v.f;
}
__device__ __forceinline__ unsigned pk2(float e, float o){   // e = even-k (low half)
  return (unsigned)bfh(e) | ((unsigned)bfh(o) << 16);
}
__device__ __forceinline__ short8 pack8hi(float4 a, float4 b){
  FI4 r;
  r.i.x = (int)pk2(a.x, a.y); r.i.y = (int)pk2(a.z, a.w);
  r.i.z = (int)pk2(b.x, b.y); r.i.w = (int)pk2(b.z, b.w);
  return r.s;
}
__device__ __forceinline__ float lof(float f){ return f - bf2f(bfh(f)); }
__device__ __forceinline__ short8 pack8lo(float4 a, float4 b){
  FI4 r;
  r.i.x = (int)pk2(lof(a.x), lof(a.y)); r.i.y = (int)pk2(lof(a.z), lof(a.w));
  r.i.z = (int)pk2(lof(b.x), lof(b.y)); r.i.w = (int)pk2(lof(b.z), lof(b.w));
  return r.s;
}

__global__ __launch_bounds__(256, 3) void k_out(const float* __restrict__ x,
                                                const float* __restrict__ Z,
                                                const float* __restrict__ cw,
                                                const float* __restrict__ cb,
                                                float* __restrict__ out){
  __shared__ unsigned xp[52*256];   // 53 KB -> 3 blocks/CU

  const int t    = threadIdx.x;
  const int lane = t & 63, wv = t >> 6;
  const int b = blockIdx.x >> 8, h = blockIdx.x & 255;

  const float* xb = x + ((size_t)b*64*65536 + (size_t)h*256);

  // ---- stage x[b,:,h,:] as packed bf16 k-pairs (row k2 = i/2) ----
#pragma unroll
  for (int p = 0; p < 8; ++p){
    int i2 = p*4 + wv;             // 0..31
    int w0 = lane*4;               // wave covers full 1KB row
    float4 r0 = *(const float4*)(xb + (size_t)(2*i2)  *65536 + w0);
    float4 r1 = *(const float4*)(xb + (size_t)(2*i2+1)*65536 + w0);
    uint4 d;
    d.x = pk2(r0.x, r1.x);
    d.y = pk2(r0.y, r1.y);
    d.z = pk2(r0.z, r1.z);
    d.w = pk2(r0.w, r1.w);
    int col = (w0 + 4*i2) & 255;   // swizzle: multiple of 4 -> 16B aligned
    *(uint4*)&xp[i2*256 + col] = d;
  }
  // ---- trig rows: (cos(2*pi*l*w/256), -sin(...)) at k2 = 32+l ----
  {
    int w = t;
    float s1, c1;
    sincosf((float)w * 0.02454369260617025967f, &s1, &c1);
    float cc = 1.f, ss = 0.f;
#pragma unroll
    for (int l = 0; l < 20; ++l){
      int k2 = 32 + l;
      xp[k2*256 + ((w + 4*k2) & 255)] = pk2(cc, -ss);
      float nc = cc*c1 - ss*s1;
      ss = ss*c1 + cc*s1;
      cc = nc;
    }
  }
  __syncthreads();

  const int g = lane >> 4, rA = lane & 15;

  // accumulators init with bias: C row o = 16*mt + 4*g + r
  f32x4 acc[4][4];
#pragma unroll
  for (int mt = 0; mt < 4; ++mt){
    float4 cbv = *(const float4*)(cb + mt*16 + g*4);
#pragma unroll
    for (int j = 0; j < 4; ++j){
      f32x4 a0; a0[0] = cbv.x; a0[1] = cbv.y; a0[2] = cbv.z; a0[3] = cbv.w;
      acc[j][mt] = a0;
    }
  }

  const int K2TAB[6] = {0, 16, 0, 16, 32, 48};   // B-side LDS row bases per ktile

#pragma unroll
  for (int pass = 0; pass < 2; ++pass){
    // ---- A fragments for this pass (row o = 16*mt + rA, k-octet by g) ----
    short8 As[4][3];
    if (pass == 0){
#pragma unroll
      for (int mt = 0; mt < 4; ++mt){
        const float* cwo = cw + (size_t)(mt*16 + rA)*64;
        float4 c0a = *(const float4*)(cwo + 8*g);
        float4 c0b = *(const float4*)(cwo + 8*g + 4);
        float4 c1a = *(const float4*)(cwo + 32 + 8*g);
        float4 c1b = *(const float4*)(cwo + 32 + 8*g + 4);
        As[mt][0] = pack8hi(c0a, c0b);   // kt0: cw_hi, i = 8g..8g+7
        As[mt][1] = pack8hi(c1a, c1b);   // kt1: cw_hi, i = 32+8g..
        As[mt][2] = pack8lo(c0a, c0b);   // kt2: cw_lo, i = 8g..
      }
    } else {
#pragma unroll
      for (int mt = 0; mt < 4; ++mt){
        const float* cwo = cw + (size_t)(mt*16 + rA)*64;
        float4 c1a = *(const float4*)(cwo + 32 + 8*g);
        float4 c1b = *(const float4*)(cwo + 32 + 8*g + 4);
        As[mt][0] = pack8lo(c1a, c1b);   // kt3: cw_lo, i = 32+8g..
        const float* zo = Z + ((size_t)(b*64 + mt*16 + rA)*256 + h)*40;
        float4 z0a = *(const float4*)(zo + 8*g);
        float4 z0b = *(const float4*)(zo + 8*g + 4);
        As[mt][1] = pack8hi(z0a, z0b);   // kt4: (zr,zi)[8g..8g+7]
        if (g == 0){
          float4 z1a = *(const float4*)(zo + 32);
          float4 z1b = *(const float4*)(zo + 36);
          As[mt][2] = pack8hi(z1a, z1b); // kt5: (zr,zi)[32..39] (l=16..19)
        } else {
          FI4 zz; zz.i.x = 0; zz.i.y = 0; zz.i.z = 0; zz.i.w = 0;
          As[mt][2] = zz.s;              // zero-pad k = 168..191
        }
      }
    }
    // ---- main MFMA loop: wave wv owns n-tiles wv*4 .. wv*4+3 ----
#pragma unroll
    for (int j = 0; j < 4; ++j){
      int w = (wv*4 + j)*16 + rA;        // B col n = lane&15
#pragma unroll
      for (int kt3 = 0; kt3 < 3; ++kt3){
        int K2 = K2TAB[pass*3 + kt3];
        FI4 bf;
#pragma unroll
        for (int e2 = 0; e2 < 4; ++e2){
          int k2  = K2 + 4*g + e2;
          int k2c = (k2 < 52) ? k2 : 0;  // kt5 pad rows: any finite data (A=0 there)
          (&bf.i.x)[e2] = (int)xp[k2c*256 + ((w + 4*k2c) & 255)];
        }
#pragma unroll
        for (int mt = 0; mt < 4; ++mt)
          acc[j][mt] = __builtin_amdgcn_mfma_f32_16x16x32_bf16(As[mt][kt3], bf.s, acc[j][mt], 0, 0, 0);
      }
    }
  }

  // ---- epilogue: GELU + store (C: col w = lane&15 + 16nt, row o = 16mt + 4g + r) ----
  float* ob = out + ((size_t)b*64*65536 + (size_t)h*256);
#pragma unroll
  for (int j = 0; j < 4; ++j){
    int w = (wv*4 + j)*16 + rA;
#pragma unroll
    for (int mt = 0; mt < 4; ++mt){
#pragma unroll
      for (int r = 0; r < 4; ++r){
        int o = mt*16 + g*4 + r;
        float v = acc[j][mt][r];
        float u  = v * (0.7978845608028654f + 0.03567740814f * v * v);
        float au = fabsf(u);
        float e  = __expf(-2.f*au);
        float th = (1.f - e) * __builtin_amdgcn_rcpf(1.f + e);
        th = copysignf(th, u);
        ob[(size_t)o*65536 + w] = 0.5f*v*(1.f + th);
      }
    }
  }
}

extern "C" void kernel_launch(void* const* d_in, const int* in_sizes, int n_in,
                              void* d_out, int out_size, void* d_ws, size_t ws_size,
                              hipStream_t stream) {
  const float* x   = (const float*)d_in[0];
  const float* wre = (const float*)d_in[1];
  const float* wim = (const float*)d_in[2];
  const float* cw  = (const float*)d_in[3];
  const float* cb  = (const float*)d_in[4];
  float* out = (float*)d_out;
  float* ws  = (float*)d_ws;

  float* twA = ws + TWA_OFF;
  float* twB = ws + TWB_OFF;
  float* Yw  = ws + YW_OFF;
  float* X   = ws + X_OFF;
  float* OF  = ws + OF_OFF;
  float* Z   = ws + Z_OFF;

  k_init <<<20,   256, 0, stream>>>(twA, twB);
  k_dftw <<<1024, 256, 0, stream>>>(x, twA, Yw);
  k_dfth <<<1024, 512, 0, stream>>>(Yw, twB, X);
  k_mix  <<<400,  256, 0, stream>>>(X, wre, wim, OF);
  k_idfth<<<1024, 256, 0, stream>>>(OF, Z);
  k_out  <<<4096, 256, 0, stream>>>(x, Z, cw, cb, out);
}

// Round 2
// 719.701 us; speedup vs baseline: 1.2854x; 1.0822x over previous
//
#include <hip/hip_runtime.h>
#include <hip/hip_bf16.h>
#include <math.h>

// Problem constants
#define BN   16
#define NCH  64      // CIN == COUT == 64
#define HH   256
#define WW   256
#define M0_  20
#define M1_  20

// Workspace layout (in floats)
#define TWA_OFF 0
#define TWA_SZ  (256*40)            // now: bf16 twA_T[48][256] (uses 6144 float slots)
#define TWB_OFF (TWA_OFF + TWA_SZ)
#define TWB_SZ  (20*256*2)          // [k][h] (cos, -sin)/256 pairs
#define YW_OFF  (TWB_OFF + TWB_SZ)
#define YW_SZ   (1024*256*40)       // (unused after fusion; kept for layout stability)
#define X_OFF   (YW_OFF + YW_SZ)
#define X_SZ    (1024*800)          // [b*64+i][k*20+l] complex
#define OF_OFF  (X_OFF + X_SZ)
#define OF_SZ   (1024*800)          // [b*64+o][k*20+l] complex (scaled)
#define Z_OFF   (OF_OFF + OF_SZ)
#define Z_SZ    (1024*256*40)       // [b*64+o][h][l] complex interleaved

// ---------------- shared helpers (bf16 pack) ----------------
typedef __attribute__((ext_vector_type(8))) short short8;
typedef __attribute__((ext_vector_type(4))) float f32x4;
union FI4 { int4 i; short8 s; };

__device__ __forceinline__ unsigned short bfh(float f){
  union { float f; unsigned u; } v; v.f = f;
  unsigned r = v.u + 0x7FFFu + ((v.u >> 16) & 1u);   // RNE to bf16
  return (unsigned short)(r >> 16);
}
__device__ __forceinline__ float bf2f(unsigned short s){
  union { unsigned u; float f; } v; v.u = ((unsigned)s) << 16;
  return v.f;
}
__device__ __forceinline__ unsigned pk2(float e, float o){   // e -> low short, o -> high short
  return (unsigned)bfh(e) | ((unsigned)bfh(o) << 16);
}
__device__ __forceinline__ short8 pack8hi(float4 a, float4 b){  // 8 floats -> 8 bf16 in order
  FI4 r;
  r.i.x = (int)pk2(a.x, a.y); r.i.y = (int)pk2(a.z, a.w);
  r.i.z = (int)pk2(b.x, b.y); r.i.w = (int)pk2(b.z, b.w);
  return r.s;
}
__device__ __forceinline__ float lof(float f){ return f - bf2f(bfh(f)); }
__device__ __forceinline__ short8 pack8lo(float4 a, float4 b){
  FI4 r;
  r.i.x = (int)pk2(lof(a.x), lof(a.y)); r.i.y = (int)pk2(lof(a.z), lof(a.w));
  r.i.z = (int)pk2(lof(b.x), lof(b.y)); r.i.w = (int)pk2(lof(b.z), lof(b.w));
  return r.s;
}

// ---------------- twiddle tables ----------------
// twA region: bf16 twA_T[j=48][w=256]; j=2l+p: p=0 -> cos(2pi*w*l/256), p=1 -> -sin(...); rows 40..47 = 0
// twB region: fp32 [k][h] (cos,-sin)/256 pairs (forward-h DFT with ortho fold)
__global__ __launch_bounds__(256) void k_init(float* __restrict__ twA, float* __restrict__ twB){
  int t = blockIdx.x*256 + threadIdx.x;      // 5120 threads
  const float step = 6.28318530717958647692f / 256.0f;
  if (t < 5120){
    int k = t >> 8, h = t & 255;
    int m = (k*h) & 255;
    float a = step * (float)m;
    twB[2*t]   =  cosf(a) * (1.0f/256.0f);
    twB[2*t+1] = -sinf(a) * (1.0f/256.0f);
  }
  unsigned short* ta = (unsigned short*)twA;
  for (int idx = t; idx < 48*256; idx += 5120){
    int j = idx >> 8, w = idx & 255;
    float v = 0.f;
    if (j < 40){
      int l = j >> 1;
      int m = (w*l) & 255;
      float a = step * (float)m;
      v = (j & 1) ? -sinf(a) : cosf(a);
    }
    ta[idx] = bfh(v);
  }
}

// ---------------- fused forward transform (MFMA w-DFT + VALU h-DFT) ----------------
// Per block bi=(b*64+i):
//   stage 1: Y[h][j] = sum_w x[bi][h][w] * twA_T[j][w]   (GEMM M=256,N=48,K=256, bf16 MFMA)
//   stage 2: X[k][l] = sum_h twB[k][h] * (Y[h][2l] + i Y[h][2l+1])   (VALU, 400 items)
__global__ __launch_bounds__(256, 2) void k_fwd(const float* __restrict__ x,
                                                const float* __restrict__ twA,
                                                const float* __restrict__ twB,
                                                float* __restrict__ X){
  __shared__ float Y[256*50];     // 50 KB, stride 50 (even -> float2-aligned; conflict-free-ish)

  const int t = threadIdx.x;
  const int lane = t & 63, wv = t >> 6;
  const int g = lane >> 4, rA = lane & 15;
  const int bi = blockIdx.x;

  // B-fragments (twA_T) straight from global into registers; L2-resident 24KB table.
  short8 Bf[3][8];
  const unsigned short* ta = (const unsigned short*)twA;
#pragma unroll
  for (int n = 0; n < 3; ++n)
#pragma unroll
    for (int ks = 0; ks < 8; ++ks)
      Bf[n][ks] = *(const short8*)(ta + ((n*16 + rA)*256 + ks*32 + g*8));

  const float* xb = x + (size_t)bi * 65536;

#pragma unroll 1
  for (int q = 0; q < 4; ++q){
    int mt = wv*4 + q;
    const float* xr = xb + (size_t)(mt*16 + rA)*256 + g*8;
    // A: 8 consecutive w per lane per k-step, direct from global (64B-segment coalesced)
    float4 xa[8], xc[8];
#pragma unroll
    for (int ks = 0; ks < 8; ++ks){
      xa[ks] = *(const float4*)(xr + ks*32);
      xc[ks] = *(const float4*)(xr + ks*32 + 4);
    }
    short8 As[8];
#pragma unroll
    for (int ks = 0; ks < 8; ++ks) As[ks] = pack8hi(xa[ks], xc[ks]);

    f32x4 acc[3];
#pragma unroll
    for (int n = 0; n < 3; ++n){ f32x4 z; z[0]=0.f; z[1]=0.f; z[2]=0.f; z[3]=0.f; acc[n] = z; }
#pragma unroll
    for (int ks = 0; ks < 8; ++ks)
#pragma unroll
      for (int n = 0; n < 3; ++n)
        acc[n] = __builtin_amdgcn_mfma_f32_16x16x32_bf16(As[ks], Bf[n][ks], acc[n], 0, 0, 0);

    // C layout: row h = mt*16 + g*4 + r, col j = n*16 + rA
#pragma unroll
    for (int n = 0; n < 3; ++n)
#pragma unroll
      for (int r = 0; r < 4; ++r)
        Y[(mt*16 + g*4 + r)*50 + n*16 + rA] = acc[n][r];
  }
  __syncthreads();

  // stage 2: h-DFT (20 modes), ortho 1/256 folded in twB
  const float2* tb2 = (const float2*)twB;
  for (int it = t; it < 400; it += 256){
    int k = it / 20, l = it - k*20;
    const float2* tb = tb2 + k*256;
    float are = 0.f, aim = 0.f;
#pragma unroll 4
    for (int h = 0; h < 256; ++h){
      float2 tv = tb[h];
      float2 yv = *(const float2*)&Y[h*50 + 2*l];
      are += yv.x*tv.x - yv.y*tv.y;
      aim += yv.x*tv.y + yv.y*tv.x;
    }
    ((float2*)X)[(size_t)bi*400 + it] = make_float2(are, aim);
  }
}

// ---------------- stage C: per-mode channel mix ----------------
__global__ __launch_bounds__(256) void k_mix(const float* __restrict__ X,
                                             const float* __restrict__ wre,
                                             const float* __restrict__ wim,
                                             float* __restrict__ OF){
  __shared__ float2 Xs[1024];
  int bk = blockIdx.x;
  int kl = (bk & 7)*50 + (bk >> 3);
  const float2* X2 = (const float2*)X;
  for (int r = threadIdx.x; r < 1024; r += 256) Xs[r] = X2[(size_t)r*400 + kl];
  __syncthreads();
  int o = threadIdx.x & 63, bg = threadIdx.x >> 6;
  float ar[4] = {0,0,0,0}, ai[4] = {0,0,0,0};
  for (int i=0;i<64;++i){
    size_t widx = (size_t)(i*64 + o)*400 + kl;
    float wr = wre[widx], wi = wim[widx];
#pragma unroll
    for (int j=0;j<4;j++){
      float2 xv = Xs[(bg*4+j)*64 + i];
      ar[j] += xv.x*wr - xv.y*wi;
      ai[j] += xv.x*wi + xv.y*wr;
    }
  }
  int l = kl % 20;
  float scale = (l==0 ? 1.0f : 2.0f) * (1.0f/256.0f);
  float2* OF2 = (float2*)OF;
#pragma unroll
  for (int j=0;j<4;j++){
    OF2[(size_t)((bg*4+j)*64 + o)*400 + kl] = make_float2(ar[j]*scale, ai[j]*scale);
  }
}

// ---------------- stage D: zero-padded inverse DFT along h ----------------
__global__ __launch_bounds__(256) void k_idfth(const float* __restrict__ OF,
                                               float* __restrict__ Z){
  __shared__ float2 fs[400];
  int bo = blockIdx.x;
  const float2* src = ((const float2*)OF) + (size_t)bo*400;
  for (int r = threadIdx.x; r < 400; r += 256) fs[r] = src[r];
  __syncthreads();
  int h = threadIdx.x;
  float s1, c1;
  sincosf((float)h * 0.02454369260617025967f, &s1, &c1);
  float zr[20], zi[20];
#pragma unroll
  for (int l=0;l<20;l++){ zr[l]=0.f; zi[l]=0.f; }
  float tr = 1.f, ti = 0.f;
  for (int k=0;k<20;++k){
#pragma unroll
    for (int l=0;l<20;l++){
      float2 f = fs[k*20+l];
      zr[l] += f.x*tr - f.y*ti;
      zi[l] += f.x*ti + f.y*tr;
    }
    float nt = tr*c1 - ti*s1;
    ti = tr*s1 + ti*c1;
    tr = nt;
  }
  float4* dst = (float4*)(Z + (((size_t)bo*256 + h)*40));
#pragma unroll
  for (int p=0;p<10;p++) dst[p] = make_float4(zr[2*p], zi[2*p], zr[2*p+1], zi[2*p+1]);
}

// ---------------- stage E (MFMA): conv(hi+lo) + spectral irfft-w + GELU ----------------
__global__ __launch_bounds__(256, 3) void k_out(const float* __restrict__ x,
                                                const float* __restrict__ Z,
                                                const float* __restrict__ cw,
                                                const float* __restrict__ cb,
                                                float* __restrict__ out){
  __shared__ unsigned xp[52*256];   // 53 KB -> 3 blocks/CU

  const int t    = threadIdx.x;
  const int lane = t & 63, wv = t >> 6;
  const int b = blockIdx.x >> 8, h = blockIdx.x & 255;

  const float* xb = x + ((size_t)b*64*65536 + (size_t)h*256);

  // ---- stage x[b,:,h,:] as packed bf16 k-pairs (row k2 = i/2) ----
#pragma unroll
  for (int p = 0; p < 8; ++p){
    int i2 = p*4 + wv;             // 0..31
    int w0 = lane*4;               // wave covers full 1KB row
    float4 r0 = *(const float4*)(xb + (size_t)(2*i2)  *65536 + w0);
    float4 r1 = *(const float4*)(xb + (size_t)(2*i2+1)*65536 + w0);
    uint4 d;
    d.x = pk2(r0.x, r1.x);
    d.y = pk2(r0.y, r1.y);
    d.z = pk2(r0.z, r1.z);
    d.w = pk2(r0.w, r1.w);
    int col = (w0 + 4*i2) & 255;   // swizzle: multiple of 4 -> 16B aligned
    *(uint4*)&xp[i2*256 + col] = d;
  }
  // ---- trig rows: (cos(2*pi*l*w/256), -sin(...)) at k2 = 32+l ----
  {
    int w = t;
    float s1, c1;
    sincosf((float)w * 0.02454369260617025967f, &s1, &c1);
    float cc = 1.f, ss = 0.f;
#pragma unroll
    for (int l = 0; l < 20; ++l){
      int k2 = 32 + l;
      xp[k2*256 + ((w + 4*k2) & 255)] = pk2(cc, -ss);
      float nc = cc*c1 - ss*s1;
      ss = ss*c1 + cc*s1;
      cc = nc;
    }
  }
  __syncthreads();

  const int g = lane >> 4, rA = lane & 15;

  // accumulators init with bias: C row o = 16*mt + 4*g + r
  f32x4 acc[4][4];
#pragma unroll
  for (int mt = 0; mt < 4; ++mt){
    float4 cbv = *(const float4*)(cb + mt*16 + g*4);
#pragma unroll
    for (int j = 0; j < 4; ++j){
      f32x4 a0; a0[0] = cbv.x; a0[1] = cbv.y; a0[2] = cbv.z; a0[3] = cbv.w;
      acc[j][mt] = a0;
    }
  }

  const int K2TAB[6] = {0, 16, 0, 16, 32, 48};   // B-side LDS row bases per ktile

#pragma unroll
  for (int pass = 0; pass < 2; ++pass){
    short8 As[4][3];
    if (pass == 0){
#pragma unroll
      for (int mt = 0; mt < 4; ++mt){
        const float* cwo = cw + (size_t)(mt*16 + rA)*64;
        float4 c0a = *(const float4*)(cwo + 8*g);
        float4 c0b = *(const float4*)(cwo + 8*g + 4);
        float4 c1a = *(const float4*)(cwo + 32 + 8*g);
        float4 c1b = *(const float4*)(cwo + 32 + 8*g + 4);
        As[mt][0] = pack8hi(c0a, c0b);   // kt0: cw_hi, i = 8g..8g+7
        As[mt][1] = pack8hi(c1a, c1b);   // kt1: cw_hi, i = 32+8g..
        As[mt][2] = pack8lo(c0a, c0b);   // kt2: cw_lo, i = 8g..
      }
    } else {
#pragma unroll
      for (int mt = 0; mt < 4; ++mt){
        const float* cwo = cw + (size_t)(mt*16 + rA)*64;
        float4 c1a = *(const float4*)(cwo + 32 + 8*g);
        float4 c1b = *(const float4*)(cwo + 32 + 8*g + 4);
        As[mt][0] = pack8lo(c1a, c1b);   // kt3: cw_lo, i = 32+8g..
        const float* zo = Z + ((size_t)(b*64 + mt*16 + rA)*256 + h)*40;
        float4 z0a = *(const float4*)(zo + 8*g);
        float4 z0b = *(const float4*)(zo + 8*g + 4);
        As[mt][1] = pack8hi(z0a, z0b);   // kt4: (zr,zi)[8g..8g+7]
        if (g == 0){
          float4 z1a = *(const float4*)(zo + 32);
          float4 z1b = *(const float4*)(zo + 36);
          As[mt][2] = pack8hi(z1a, z1b); // kt5: (zr,zi)[32..39] (l=16..19)
        } else {
          FI4 zz; zz.i.x = 0; zz.i.y = 0; zz.i.z = 0; zz.i.w = 0;
          As[mt][2] = zz.s;              // zero-pad k = 168..191
        }
      }
    }
#pragma unroll
    for (int j = 0; j < 4; ++j){
      int w = (wv*4 + j)*16 + rA;
#pragma unroll
      for (int kt3 = 0; kt3 < 3; ++kt3){
        int K2 = K2TAB[pass*3 + kt3];
        FI4 bf;
#pragma unroll
        for (int e2 = 0; e2 < 4; ++e2){
          int k2  = K2 + 4*g + e2;
          int k2c = (k2 < 52) ? k2 : 0;
          (&bf.i.x)[e2] = (int)xp[k2c*256 + ((w + 4*k2c) & 255)];
        }
#pragma unroll
        for (int mt = 0; mt < 4; ++mt)
          acc[j][mt] = __builtin_amdgcn_mfma_f32_16x16x32_bf16(As[mt][kt3], bf.s, acc[j][mt], 0, 0, 0);
      }
    }
  }

  // ---- epilogue: GELU + store ----
  float* ob = out + ((size_t)b*64*65536 + (size_t)h*256);
#pragma unroll
  for (int j = 0; j < 4; ++j){
    int w = (wv*4 + j)*16 + rA;
#pragma unroll
    for (int mt = 0; mt < 4; ++mt){
#pragma unroll
      for (int r = 0; r < 4; ++r){
        int o = mt*16 + g*4 + r;
        float v = acc[j][mt][r];
        float u  = v * (0.7978845608028654f + 0.03567740814f * v * v);
        float au = fabsf(u);
        float e  = __expf(-2.f*au);
        float th = (1.f - e) * __builtin_amdgcn_rcpf(1.f + e);
        th = copysignf(th, u);
        ob[(size_t)o*65536 + w] = 0.5f*v*(1.f + th);
      }
    }
  }
}

extern "C" void kernel_launch(void* const* d_in, const int* in_sizes, int n_in,
                              void* d_out, int out_size, void* d_ws, size_t ws_size,
                              hipStream_t stream) {
  const float* x   = (const float*)d_in[0];
  const float* wre = (const float*)d_in[1];
  const float* wim = (const float*)d_in[2];
  const float* cw  = (const float*)d_in[3];
  const float* cb  = (const float*)d_in[4];
  float* out = (float*)d_out;
  float* ws  = (float*)d_ws;

  float* twA = ws + TWA_OFF;
  float* twB = ws + TWB_OFF;
  float* X   = ws + X_OFF;
  float* OF  = ws + OF_OFF;
  float* Z   = ws + Z_OFF;

  k_init <<<20,   256, 0, stream>>>(twA, twB);
  k_fwd  <<<1024, 256, 0, stream>>>(x, twA, twB, X);
  k_mix  <<<400,  256, 0, stream>>>(X, wre, wim, OF);
  k_idfth<<<1024, 256, 0, stream>>>(OF, Z);
  k_out  <<<4096, 256, 0, stream>>>(x, Z, cw, cb, out);
}